// Round 1
// baseline (181.606 us; speedup 1.0000x reference)
//
#include <hip/hip_runtime.h>
#include <math.h>

// BaseHybridHead: pre-GEMM (8192x512 @ 512x10) -> tanh*pi/2 -> 10-qubit real
// statevector sim (RY/CNOT ladder, 6 layers) -> <Z_w> -> post-GEMM (10->2).
//
// Design: ONE wave per sample. Statevector (1024 fp32) = 16 regs x 64 lanes.
//   element index e[9:0]: bits [9:4] = lane, bits [3:0] = register index.
//   wire w acts on bit (9-w)  (PennyLane: wire 0 = MSB).
//   - gates on lane bits  -> __shfl_xor / __shfl permutes
//   - gates on reg bits   -> static register arithmetic (compile-time)
// Initial H-layer on |0..0> == uniform state: init all amps to 1/32.

#define NQ   10
#define NREG 16

template<int B>
__device__ __forceinline__ void ry_lane(float (&s)[NREG], int lane, float c, float si) {
    // RY on a lane bit B: partner across lanes, sign by own bit.
    float sgn = ((lane >> B) & 1) ? si : -si;
    #pragma unroll
    for (int r = 0; r < NREG; ++r) {
        float o = __shfl_xor(s[r], 1 << B);
        s[r] = fmaf(sgn, o, c * s[r]);
    }
}

template<int P>
__device__ __forceinline__ void ry_reg(float (&s)[NREG], float c, float si) {
    // RY on a reg bit P: pair (r, r|m) in-register.
    const int m = 1 << P;
    #pragma unroll
    for (int r = 0; r < NREG; ++r) {
        if ((r & m) == 0) {
            float a = s[r], b = s[r + m];
            s[r]     = fmaf(c, a, -si * b);
            s[r + m] = fmaf(si, a,  c * b);
        }
    }
}

template<int BC, int BT>
__device__ __forceinline__ void cnot_lane(float (&s)[NREG], int lane) {
    // control lane-bit BC, target lane-bit BT: pure lane permutation
    int src = ((lane >> BC) & 1) ? (lane ^ (1 << BT)) : lane;
    #pragma unroll
    for (int r = 0; r < NREG; ++r) s[r] = __shfl(s[r], src);
}

__device__ __forceinline__ void cnot_5_6(float (&s)[NREG], int lane) {
    // control = lane bit 0, target = reg bit 3: conditional reg swap
    bool sel = (lane & 1) != 0;
    #pragma unroll
    for (int r = 0; r < 8; ++r) {
        float a = s[r], b = s[r + 8];
        s[r]     = sel ? b : a;
        s[r + 8] = sel ? a : b;
    }
}

template<int PC, int PT>
__device__ __forceinline__ void cnot_reg(float (&s)[NREG]) {
    // control reg-bit PC, target reg-bit PT: static register swap
    #pragma unroll
    for (int r = 0; r < NREG; ++r) {
        if (((r >> PC) & 1) && !((r >> PT) & 1)) {
            float t = s[r];
            s[r] = s[r ^ (1 << PT)];
            s[r ^ (1 << PT)] = t;
        }
    }
}

#define APPLY_RY_ALL(CARR, SARR, BASE)                                        \
    { float c_, s_;                                                           \
      c_=__shfl(CARR,(BASE)+0); s_=__shfl(SARR,(BASE)+0); ry_lane<5>(s,lane,c_,s_); \
      c_=__shfl(CARR,(BASE)+1); s_=__shfl(SARR,(BASE)+1); ry_lane<4>(s,lane,c_,s_); \
      c_=__shfl(CARR,(BASE)+2); s_=__shfl(SARR,(BASE)+2); ry_lane<3>(s,lane,c_,s_); \
      c_=__shfl(CARR,(BASE)+3); s_=__shfl(SARR,(BASE)+3); ry_lane<2>(s,lane,c_,s_); \
      c_=__shfl(CARR,(BASE)+4); s_=__shfl(SARR,(BASE)+4); ry_lane<1>(s,lane,c_,s_); \
      c_=__shfl(CARR,(BASE)+5); s_=__shfl(SARR,(BASE)+5); ry_lane<0>(s,lane,c_,s_); \
      c_=__shfl(CARR,(BASE)+6); s_=__shfl(SARR,(BASE)+6); ry_reg<3>(s,c_,s_);       \
      c_=__shfl(CARR,(BASE)+7); s_=__shfl(SARR,(BASE)+7); ry_reg<2>(s,c_,s_);       \
      c_=__shfl(CARR,(BASE)+8); s_=__shfl(SARR,(BASE)+8); ry_reg<1>(s,c_,s_);       \
      c_=__shfl(CARR,(BASE)+9); s_=__shfl(SARR,(BASE)+9); ry_reg<0>(s,c_,s_); }

__global__ __launch_bounds__(256) void hybrid_head_kernel(
    const float* __restrict__ X,      // (B, 512)
    const float* __restrict__ Wpre,   // (10, 512)
    const float* __restrict__ bpre,   // (10,)
    const float* __restrict__ qp,     // (150,) = (15,10)
    const float* __restrict__ Wpost,  // (2, 10)
    const float* __restrict__ bpost,  // (2,)
    float* __restrict__ out,          // (B, 2)
    int B)
{
    const int lane   = threadIdx.x & 63;
    const int wave   = threadIdx.x >> 6;
    const int sample = blockIdx.x * 4 + wave;
    if (sample >= B) return;  // wave-uniform

    // ---------- pre GEMM: acc[q] = X[sample,:] . Wpre[q,:] ----------
    const float* xrow = X + (size_t)sample * 512;
    float4 x0 = ((const float4*)xrow)[lane];       // k = 4*lane..+3
    float4 x1 = ((const float4*)xrow)[64 + lane];  // k = 256+4*lane..+3
    float acc[NQ];
    #pragma unroll
    for (int q = 0; q < NQ; ++q) {
        const float* wr = Wpre + q * 512;
        float4 w0 = ((const float4*)wr)[lane];
        float4 w1 = ((const float4*)wr)[64 + lane];
        float a;
        a = x0.x * w0.x;
        a = fmaf(x0.y, w0.y, a); a = fmaf(x0.z, w0.z, a); a = fmaf(x0.w, w0.w, a);
        a = fmaf(x1.x, w1.x, a); a = fmaf(x1.y, w1.y, a);
        a = fmaf(x1.z, w1.z, a); a = fmaf(x1.w, w1.w, a);
        acc[q] = a;
    }
    #pragma unroll
    for (int q = 0; q < NQ; ++q) {
        float v = acc[q];
        #pragma unroll
        for (int d = 32; d >= 1; d >>= 1) v += __shfl_xor(v, d);
        acc[q] = v;  // all lanes hold full dot product
    }

    // lane w (<10) picks acc[w], computes its rotation's cos/sin
    float pre = acc[0];
    #pragma unroll
    for (int q = 1; q < NQ; ++q) pre = (lane == q) ? acc[q] : pre;
    float cth = 1.0f, sth = 0.0f;
    if (lane < NQ) {
        float th = tanhf(pre + bpre[lane]) * 1.5707963267948966f;
        sincosf(0.5f * th, &sth, &cth);
    }

    // lane l (<60) holds cos/sin of layer weight qp[10 + l] (rows 1..6)
    float cw = 1.0f, sw = 0.0f;
    if (lane < 60) {
        sincosf(0.5f * qp[10 + lane], &sw, &cw);
    }

    // ---------- statevector: H^10 |0..0> = uniform ----------
    float s[NREG];
    #pragma unroll
    for (int r = 0; r < NREG; ++r) s[r] = 0.03125f;  // 1/sqrt(1024)

    // data-dependent RY layer
    APPLY_RY_ALL(cth, sth, 0);

    // 6 entangling layers
    for (int k = 0; k < 6; ++k) {
        // even CNOTs: (0,1)(2,3)(4,5)(6,7)(8,9) -> bits (9,8)(7,6)(5,4)(3,2)(1,0)
        cnot_lane<5, 4>(s, lane);
        cnot_lane<3, 2>(s, lane);
        cnot_lane<1, 0>(s, lane);
        cnot_reg<3, 2>(s);
        cnot_reg<1, 0>(s);
        // odd CNOTs: (1,2)(3,4)(5,6)(7,8) -> bits (8,7)(6,5)(4,3)(2,1)
        cnot_lane<4, 3>(s, lane);
        cnot_lane<2, 1>(s, lane);
        cnot_5_6(s, lane);
        cnot_reg<2, 1>(s);
        // trainable RY layer k+1
        APPLY_RY_ALL(cw, sw, k * 10);
    }

    // ---------- <Z_w> ----------
    float p[NREG];
    float tot = 0.0f;
    #pragma unroll
    for (int r = 0; r < NREG; ++r) { p[r] = s[r] * s[r]; tot += p[r]; }

    float z[NQ];
    #pragma unroll
    for (int w = 0; w < 6; ++w) {
        int b = 5 - w;  // lane bit for wire w
        z[w] = ((lane >> b) & 1) ? -tot : tot;
    }
    z[6] = z[7] = z[8] = z[9] = 0.0f;
    #pragma unroll
    for (int r = 0; r < NREG; ++r) {
        z[6] += ((r >> 3) & 1) ? -p[r] : p[r];
        z[7] += ((r >> 2) & 1) ? -p[r] : p[r];
        z[8] += ((r >> 1) & 1) ? -p[r] : p[r];
        z[9] += ((r >> 0) & 1) ? -p[r] : p[r];
    }
    #pragma unroll
    for (int w = 0; w < NQ; ++w) {
        float v = z[w];
        #pragma unroll
        for (int d = 32; d >= 1; d >>= 1) v += __shfl_xor(v, d);
        z[w] = v;
    }

    // ---------- post GEMM: out[c] = b_post[c] + sum_w z_w * Wpost[c,w] ----------
    if (lane < 2) {
        const float* wp = Wpost + lane * NQ;
        float o = bpost[lane];
        #pragma unroll
        for (int w = 0; w < NQ; ++w) o = fmaf(z[w], wp[w], o);
        out[(size_t)sample * 2 + lane] = o;
    }
}

extern "C" void kernel_launch(void* const* d_in, const int* in_sizes, int n_in,
                              void* d_out, int out_size, void* d_ws, size_t ws_size,
                              hipStream_t stream) {
    const float* X     = (const float*)d_in[0];
    const float* Wpre  = (const float*)d_in[1];
    const float* bpre  = (const float*)d_in[2];
    const float* qp    = (const float*)d_in[3];
    const float* Wpost = (const float*)d_in[4];
    const float* bpost = (const float*)d_in[5];
    float* out = (float*)d_out;

    int B = in_sizes[0] / 512;  // 8192
    dim3 grid((B + 3) / 4), block(256);
    hipLaunchKernelGGL(hybrid_head_kernel, grid, block, 0, stream,
                       X, Wpre, bpre, qp, Wpost, bpost, out, B);
}

// Round 2
// 129.882 us; speedup vs baseline: 1.3982x; 1.3982x over previous
//
#include <hip/hip_runtime.h>
#include <math.h>

// BaseHybridHead restructured:
//   K1: pre-GEMM + rank-1 tensor expansion -> psi0 (8192x1024 f16)
//   K2: build A rows (trainable circuit ^T applied to basis vectors) -> Arm (1024x1024 f16)
//   K3: MFMA f16 GEMM  psif = psi0 @ Arm^T   (M=8192,N=1024,K=1024)
//   K4: z_w = sum +-psif^2  -> post head -> out (8192x2 f32)
// Trainable layers share angles across the batch => whole circuit after the
// data-RY layer is ONE fixed 1024x1024 orthogonal matrix A.

#define NQ   10
#define NREG 16
#define DIM  1024

typedef _Float16 f16;
typedef _Float16 f16x8 __attribute__((ext_vector_type(8)));
typedef float    f32x4 __attribute__((ext_vector_type(4)));

// ---------------------------------------------------------------- gate ops
template<int BB>
__device__ __forceinline__ void ry_lane(float (&s)[NREG], int lane, float c, float si) {
    float sgn = ((lane >> BB) & 1) ? si : -si;
    #pragma unroll
    for (int r = 0; r < NREG; ++r) {
        float o = __shfl_xor(s[r], 1 << BB);
        s[r] = fmaf(sgn, o, c * s[r]);
    }
}
template<int P>
__device__ __forceinline__ void ry_reg(float (&s)[NREG], float c, float si) {
    const int m = 1 << P;
    #pragma unroll
    for (int r = 0; r < NREG; ++r) {
        if ((r & m) == 0) {
            float a = s[r], b = s[r + m];
            s[r]     = fmaf(c, a, -si * b);
            s[r + m] = fmaf(si, a,  c * b);
        }
    }
}
__device__ __forceinline__ void cnot_5_6(float (&s)[NREG], int lane) {
    bool sel = (lane & 1) != 0;
    #pragma unroll
    for (int r = 0; r < 8; ++r) {
        float a = s[r], b = s[r + 8];
        s[r]     = sel ? b : a;
        s[r + 8] = sel ? a : b;
    }
}
template<int PC, int PT>
__device__ __forceinline__ void cnot_reg(float (&s)[NREG]) {
    #pragma unroll
    for (int r = 0; r < NREG; ++r) {
        if (((r >> PC) & 1) && !((r >> PT) & 1)) {
            float t = s[r];
            s[r] = s[r ^ (1 << PT)];
            s[r ^ (1 << PT)] = t;
        }
    }
}
// fused disjoint lane CNOT permutations (one bpermute pass each)
__device__ __forceinline__ void perm_even(float (&s)[NREG], int lane) {
    int src = lane ^ (((((lane >> 5) & 1) << 4)) | ((((lane >> 3) & 1) << 2)) | (((lane >> 1) & 1)));
    #pragma unroll
    for (int r = 0; r < NREG; ++r) s[r] = __shfl(s[r], src);
}
__device__ __forceinline__ void perm_odd(float (&s)[NREG], int lane) {
    int src = lane ^ (((((lane >> 4) & 1) << 3)) | ((((lane >> 2) & 1) << 1)));
    #pragma unroll
    for (int r = 0; r < NREG; ++r) s[r] = __shfl(s[r], src);
}

#define APPLY_RY_ALL(CARR, SARR, BASE)                                        \
    { float c_, s_;                                                           \
      c_=__shfl(CARR,(BASE)+0); s_=__shfl(SARR,(BASE)+0); ry_lane<5>(s,lane,c_,s_); \
      c_=__shfl(CARR,(BASE)+1); s_=__shfl(SARR,(BASE)+1); ry_lane<4>(s,lane,c_,s_); \
      c_=__shfl(CARR,(BASE)+2); s_=__shfl(SARR,(BASE)+2); ry_lane<3>(s,lane,c_,s_); \
      c_=__shfl(CARR,(BASE)+3); s_=__shfl(SARR,(BASE)+3); ry_lane<2>(s,lane,c_,s_); \
      c_=__shfl(CARR,(BASE)+4); s_=__shfl(SARR,(BASE)+4); ry_lane<1>(s,lane,c_,s_); \
      c_=__shfl(CARR,(BASE)+5); s_=__shfl(SARR,(BASE)+5); ry_lane<0>(s,lane,c_,s_); \
      c_=__shfl(CARR,(BASE)+6); s_=__shfl(SARR,(BASE)+6); ry_reg<3>(s,c_,s_);       \
      c_=__shfl(CARR,(BASE)+7); s_=__shfl(SARR,(BASE)+7); ry_reg<2>(s,c_,s_);       \
      c_=__shfl(CARR,(BASE)+8); s_=__shfl(SARR,(BASE)+8); ry_reg<1>(s,c_,s_);       \
      c_=__shfl(CARR,(BASE)+9); s_=__shfl(SARR,(BASE)+9); ry_reg<0>(s,c_,s_); }

// ---------------------------------------------------------------- K1
__global__ __launch_bounds__(256) void k1_psi0(
    const float* __restrict__ X, const float* __restrict__ Wpre,
    const float* __restrict__ bpre, f16* __restrict__ psi0, int B)
{
    const int lane = threadIdx.x & 63;
    const int wave = threadIdx.x >> 6;
    const int sample = blockIdx.x * 4 + wave;
    if (sample >= B) return;

    const float* xrow = X + (size_t)sample * 512;
    float4 x0 = ((const float4*)xrow)[lane];
    float4 x1 = ((const float4*)xrow)[64 + lane];
    float acc[NQ];
    #pragma unroll
    for (int q = 0; q < NQ; ++q) {
        const float* wr = Wpre + q * 512;
        float4 w0 = ((const float4*)wr)[lane];
        float4 w1 = ((const float4*)wr)[64 + lane];
        float a = x0.x * w0.x;
        a = fmaf(x0.y, w0.y, a); a = fmaf(x0.z, w0.z, a); a = fmaf(x0.w, w0.w, a);
        a = fmaf(x1.x, w1.x, a); a = fmaf(x1.y, w1.y, a);
        a = fmaf(x1.z, w1.z, a); a = fmaf(x1.w, w1.w, a);
        acc[q] = a;
    }
    #pragma unroll
    for (int q = 0; q < NQ; ++q) {
        float v = acc[q];
        #pragma unroll
        for (int d = 32; d >= 1; d >>= 1) v += __shfl_xor(v, d);
        acc[q] = v;
    }
    float pre = acc[0];
    #pragma unroll
    for (int q = 1; q < NQ; ++q) pre = (lane == q) ? acc[q] : pre;

    float c45 = 0.0f, s45 = 0.0f;
    if (lane < NQ) {
        float th = tanhf(pre + bpre[lane]) * 1.5707963267948966f;
        sincosf(0.5f * th + 0.7853981633974483f, &s45, &c45);
        // f(0)=cos(th/2+pi/4)=c45, f(1)=sin(th/2+pi/4)=s45
    }

    float lv = 1.0f;
    #pragma unroll
    for (int w = 0; w < 6; ++w) {
        float f0 = __shfl(c45, w), f1 = __shfl(s45, w);
        lv *= ((lane >> (5 - w)) & 1) ? f1 : f0;
    }
    float c6 = __shfl(c45, 6), s6 = __shfl(s45, 6);
    float c7 = __shfl(c45, 7), s7 = __shfl(s45, 7);
    float c8 = __shfl(c45, 8), s8 = __shfl(s45, 8);
    float c9 = __shfl(c45, 9), s9 = __shfl(s45, 9);
    float g01[4] = {c6 * c7, c6 * s7, s6 * c7, s6 * s7};
    float g23[4] = {c8 * c9, c8 * s9, s8 * c9, s8 * s9};

    union { f16 h[16]; float4 v[2]; } u;
    #pragma unroll
    for (int r = 0; r < NREG; ++r)
        u.h[r] = (f16)(lv * g01[r >> 2] * g23[r & 3]);
    float4* dst = (float4*)((char*)psi0 + (size_t)sample * 2048 + lane * 32);
    dst[0] = u.v[0];
    dst[1] = u.v[1];
}

// ---------------------------------------------------------------- K2
__global__ __launch_bounds__(256) void k2_arows(
    const float* __restrict__ qp, f16* __restrict__ Arm)
{
    const int lane = threadIdx.x & 63;
    const int wave = threadIdx.x >> 6;
    const int row = blockIdx.x * 4 + wave;  // 0..1023, row of A

    float cw = 1.0f, swn = 0.0f;
    if (lane < 60) {
        float s_, c_;
        sincosf(0.5f * qp[10 + lane], &s_, &c_);
        cw = c_; swn = -s_;  // inverse rotations
    }

    float s[NREG];
    int srcLane = row >> 4, srcReg = row & 15;
    #pragma unroll
    for (int r = 0; r < NREG; ++r)
        s[r] = (lane == srcLane && r == srcReg) ? 1.0f : 0.0f;

    // A^T e_row : for k=6..1 apply RY(-theta_k), odd CNOTs, even CNOTs
    for (int kk = 6; kk >= 1; --kk) {
        APPLY_RY_ALL(cw, swn, (kk - 1) * 10);
        // odd set: (1,2)(3,4)(5,6)(7,8)
        perm_odd(s, lane);
        cnot_5_6(s, lane);
        cnot_reg<2, 1>(s);
        // even set: (0,1)(2,3)(4,5)(6,7)(8,9)
        perm_even(s, lane);
        cnot_reg<3, 2>(s);
        cnot_reg<1, 0>(s);
    }

    union { f16 h[16]; float4 v[2]; } u;
    #pragma unroll
    for (int r = 0; r < NREG; ++r) u.h[r] = (f16)s[r];
    float4* dst = (float4*)((char*)Arm + (size_t)row * 2048 + lane * 32);
    dst[0] = u.v[0];
    dst[1] = u.v[1];
}

// ---------------------------------------------------------------- K3 GEMM
__device__ __forceinline__ void async16(const void* g, void* l) {
    __builtin_amdgcn_global_load_lds(
        (const __attribute__((address_space(1))) void*)g,
        (__attribute__((address_space(3))) void*)l, 16, 0, 0);
}

__global__ __launch_bounds__(256) void k3_gemm(
    const f16* __restrict__ P0, const f16* __restrict__ Arm, f16* __restrict__ Pf)
{
    __shared__ f16 As[128 * 32];
    __shared__ f16 Bs[128 * 32];
    const int tid = threadIdx.x, lane = tid & 63;
    const int wv = tid >> 6;
    const int wm = (wv >> 1) * 64, wn = (wv & 1) * 64;
    const size_t tM = (size_t)blockIdx.x * 128, tN = (size_t)blockIdx.y * 128;

    f32x4 acc[4][4] = {};

    const int c0 = tid, c1 = tid + 256;
    const int r0 = c0 >> 2, o0 = (c0 & 3) * 8;
    const int r1 = c1 >> 2, o1 = (c1 & 3) * 8;
    const f16* gA0 = P0 + (tM + r0) * 1024 + o0;
    const f16* gA1 = P0 + (tM + r1) * 1024 + o1;
    const f16* gB0 = Arm + (tN + r0) * 1024 + o0;
    const f16* gB1 = Arm + (tN + r1) * 1024 + o1;

    const int aoff = (lane & 15) * 32 + (lane >> 4) * 8;  // elements
    const f16* Af = As + wm * 32 + aoff;
    const f16* Bf = Bs + wn * 32 + aoff;

    for (int kt = 0; kt < 1024; kt += 32) {
        async16(gA0 + kt, As + c0 * 8);
        async16(gA1 + kt, As + c1 * 8);
        async16(gB0 + kt, Bs + c0 * 8);
        async16(gB1 + kt, Bs + c1 * 8);
        __syncthreads();
        f16x8 af[4], bf[4];
        #pragma unroll
        for (int i = 0; i < 4; ++i) af[i] = *(const f16x8*)(Af + i * 512);
        #pragma unroll
        for (int j = 0; j < 4; ++j) bf[j] = *(const f16x8*)(Bf + j * 512);
        #pragma unroll
        for (int i = 0; i < 4; ++i)
            #pragma unroll
            for (int j = 0; j < 4; ++j)
                acc[i][j] = __builtin_amdgcn_mfma_f32_16x16x32_f16(af[i], bf[j], acc[i][j], 0, 0, 0);
        __syncthreads();
    }

    const int cn = lane & 15, rq = (lane >> 4) * 4;
    #pragma unroll
    for (int i = 0; i < 4; ++i)
        #pragma unroll
        for (int t = 0; t < 4; ++t) {
            size_t m = tM + wm + i * 16 + rq + t;
            f16* dst = Pf + m * 1024 + tN + wn + cn;
            #pragma unroll
            for (int j = 0; j < 4; ++j) dst[j * 16] = (f16)acc[i][j][t];
        }
}

// ---------------------------------------------------------------- K4
__global__ __launch_bounds__(256) void k4_measure(
    const f16* __restrict__ Pf, const float* __restrict__ Wpost,
    const float* __restrict__ bpost, float* __restrict__ out, int B)
{
    const int lane = threadIdx.x & 63;
    const int wave = threadIdx.x >> 6;
    const int sample = blockIdx.x * 4 + wave;
    if (sample >= B) return;

    union { f16 h[16]; float4 v[2]; } u;
    const float4* src = (const float4*)((const char*)Pf + (size_t)sample * 2048 + lane * 32);
    u.v[0] = src[0];
    u.v[1] = src[1];

    float p[NREG], tot = 0.0f;
    #pragma unroll
    for (int r = 0; r < NREG; ++r) { float a = (float)u.h[r]; p[r] = a * a; tot += p[r]; }

    float z[NQ];
    #pragma unroll
    for (int w = 0; w < 6; ++w) {
        int b = 5 - w;
        z[w] = ((lane >> b) & 1) ? -tot : tot;
    }
    z[6] = z[7] = z[8] = z[9] = 0.0f;
    #pragma unroll
    for (int r = 0; r < NREG; ++r) {
        z[6] += ((r >> 3) & 1) ? -p[r] : p[r];
        z[7] += ((r >> 2) & 1) ? -p[r] : p[r];
        z[8] += ((r >> 1) & 1) ? -p[r] : p[r];
        z[9] += ((r >> 0) & 1) ? -p[r] : p[r];
    }
    #pragma unroll
    for (int w = 0; w < NQ; ++w) {
        float v = z[w];
        #pragma unroll
        for (int d = 32; d >= 1; d >>= 1) v += __shfl_xor(v, d);
        z[w] = v;
    }
    if (lane < 2) {
        const float* wp = Wpost + lane * NQ;
        float o = bpost[lane];
        #pragma unroll
        for (int w = 0; w < NQ; ++w) o = fmaf(z[w], wp[w], o);
        out[(size_t)sample * 2 + lane] = o;
    }
}

// ---------------------------------------------------------------- fallback (R1 kernel)
template<int BC, int BT>
__device__ __forceinline__ void cnot_lane(float (&s)[NREG], int lane) {
    int src = ((lane >> BC) & 1) ? (lane ^ (1 << BT)) : lane;
    #pragma unroll
    for (int r = 0; r < NREG; ++r) s[r] = __shfl(s[r], src);
}

__global__ __launch_bounds__(256) void hybrid_head_fallback(
    const float* __restrict__ X, const float* __restrict__ Wpre,
    const float* __restrict__ bpre, const float* __restrict__ qp,
    const float* __restrict__ Wpost, const float* __restrict__ bpost,
    float* __restrict__ out, int B)
{
    const int lane = threadIdx.x & 63;
    const int wave = threadIdx.x >> 6;
    const int sample = blockIdx.x * 4 + wave;
    if (sample >= B) return;

    const float* xrow = X + (size_t)sample * 512;
    float4 x0 = ((const float4*)xrow)[lane];
    float4 x1 = ((const float4*)xrow)[64 + lane];
    float acc[NQ];
    #pragma unroll
    for (int q = 0; q < NQ; ++q) {
        const float* wr = Wpre + q * 512;
        float4 w0 = ((const float4*)wr)[lane];
        float4 w1 = ((const float4*)wr)[64 + lane];
        float a = x0.x * w0.x;
        a = fmaf(x0.y, w0.y, a); a = fmaf(x0.z, w0.z, a); a = fmaf(x0.w, w0.w, a);
        a = fmaf(x1.x, w1.x, a); a = fmaf(x1.y, w1.y, a);
        a = fmaf(x1.z, w1.z, a); a = fmaf(x1.w, w1.w, a);
        acc[q] = a;
    }
    #pragma unroll
    for (int q = 0; q < NQ; ++q) {
        float v = acc[q];
        #pragma unroll
        for (int d = 32; d >= 1; d >>= 1) v += __shfl_xor(v, d);
        acc[q] = v;
    }
    float pre = acc[0];
    #pragma unroll
    for (int q = 1; q < NQ; ++q) pre = (lane == q) ? acc[q] : pre;
    float cth = 1.0f, sth = 0.0f;
    if (lane < NQ) {
        float th = tanhf(pre + bpre[lane]) * 1.5707963267948966f;
        sincosf(0.5f * th, &sth, &cth);
    }
    float cw = 1.0f, sw = 0.0f;
    if (lane < 60) sincosf(0.5f * qp[10 + lane], &sw, &cw);

    float s[NREG];
    #pragma unroll
    for (int r = 0; r < NREG; ++r) s[r] = 0.03125f;
    APPLY_RY_ALL(cth, sth, 0);
    for (int k = 0; k < 6; ++k) {
        perm_even(s, lane);
        cnot_reg<3, 2>(s);
        cnot_reg<1, 0>(s);
        perm_odd(s, lane);
        cnot_5_6(s, lane);
        cnot_reg<2, 1>(s);
        APPLY_RY_ALL(cw, sw, k * 10);
    }
    float p[NREG], tot = 0.0f;
    #pragma unroll
    for (int r = 0; r < NREG; ++r) { p[r] = s[r] * s[r]; tot += p[r]; }
    float z[NQ];
    #pragma unroll
    for (int w = 0; w < 6; ++w) z[w] = ((lane >> (5 - w)) & 1) ? -tot : tot;
    z[6] = z[7] = z[8] = z[9] = 0.0f;
    #pragma unroll
    for (int r = 0; r < NREG; ++r) {
        z[6] += ((r >> 3) & 1) ? -p[r] : p[r];
        z[7] += ((r >> 2) & 1) ? -p[r] : p[r];
        z[8] += ((r >> 1) & 1) ? -p[r] : p[r];
        z[9] += ((r >> 0) & 1) ? -p[r] : p[r];
    }
    #pragma unroll
    for (int w = 0; w < NQ; ++w) {
        float v = z[w];
        #pragma unroll
        for (int d = 32; d >= 1; d >>= 1) v += __shfl_xor(v, d);
        z[w] = v;
    }
    if (lane < 2) {
        const float* wp = Wpost + lane * NQ;
        float o = bpost[lane];
        #pragma unroll
        for (int w = 0; w < NQ; ++w) o = fmaf(z[w], wp[w], o);
        out[(size_t)sample * 2 + lane] = o;
    }
}

// ---------------------------------------------------------------- launch
extern "C" void kernel_launch(void* const* d_in, const int* in_sizes, int n_in,
                              void* d_out, int out_size, void* d_ws, size_t ws_size,
                              hipStream_t stream) {
    const float* X     = (const float*)d_in[0];
    const float* Wpre  = (const float*)d_in[1];
    const float* bpre  = (const float*)d_in[2];
    const float* qp    = (const float*)d_in[3];
    const float* Wpost = (const float*)d_in[4];
    const float* bpost = (const float*)d_in[5];
    float* out = (float*)d_out;
    int B = in_sizes[0] / 512;  // 8192

    size_t psi0_bytes = (size_t)B * DIM * sizeof(f16);        // 16 MB
    size_t arm_bytes  = (size_t)DIM * DIM * sizeof(f16);      // 2 MB
    size_t psif_bytes = (size_t)B * DIM * sizeof(f16);        // 16 MB
    size_t need = psi0_bytes + arm_bytes + psif_bytes;

    if (ws_size < need) {
        hipLaunchKernelGGL(hybrid_head_fallback, dim3((B + 3) / 4), dim3(256), 0, stream,
                           X, Wpre, bpre, qp, Wpost, bpost, out, B);
        return;
    }

    char* ws = (char*)d_ws;
    f16* psi0 = (f16*)ws;
    f16* Arm  = (f16*)(ws + psi0_bytes);
    f16* psif = (f16*)(ws + psi0_bytes + arm_bytes);

    hipLaunchKernelGGL(k1_psi0, dim3((B + 3) / 4), dim3(256), 0, stream, X, Wpre, bpre, psi0, B);
    hipLaunchKernelGGL(k2_arows, dim3(DIM / 4), dim3(256), 0, stream, qp, Arm);
    hipLaunchKernelGGL(k3_gemm, dim3(B / 128, DIM / 128), dim3(256), 0, stream, psi0, Arm, psif);
    hipLaunchKernelGGL(k4_measure, dim3((B + 3) / 4), dim3(256), 0, stream, psif, Wpost, bpost, out, B);
}

// Round 4
// 126.220 us; speedup vs baseline: 1.4388x; 1.0290x over previous
//
#include <hip/hip_runtime.h>
#include <math.h>

// BaseHybridHead, 3 stream-ordered kernels (stream order = phase sync):
//  KA: pre-GEMM + rank-1 expand -> psi0 (8192x1024 f16); Arm rows (1024x1024 f16)
//  KB: MFMA GEMM psif = psi0 @ Arm^T (BK=64, XOR-swizzled LDS) with fused
//      +-square measurement epilogue -> zpart[8][8192][10] f32 (no psif in HBM)
//  KC: z = sum_nb zpart; out = z @ Wpost^T + bpost

#define NQ   10
#define NREG 16
#define DIM  1024

typedef _Float16 f16;
typedef _Float16 f16x8 __attribute__((ext_vector_type(8)));
typedef float    f32x4 __attribute__((ext_vector_type(4)));

// ---------------------------------------------------------------- gate ops
template<int BB>
__device__ __forceinline__ void ry_lane(float (&s)[NREG], int lane, float c, float si) {
    float sgn = ((lane >> BB) & 1) ? si : -si;
    #pragma unroll
    for (int r = 0; r < NREG; ++r) {
        float o = __shfl_xor(s[r], 1 << BB);
        s[r] = fmaf(sgn, o, c * s[r]);
    }
}
template<int P>
__device__ __forceinline__ void ry_reg(float (&s)[NREG], float c, float si) {
    const int m = 1 << P;
    #pragma unroll
    for (int r = 0; r < NREG; ++r) {
        if ((r & m) == 0) {
            float a = s[r], b = s[r + m];
            s[r]     = fmaf(c, a, -si * b);
            s[r + m] = fmaf(si, a,  c * b);
        }
    }
}
__device__ __forceinline__ void cnot_5_6(float (&s)[NREG], int lane) {
    bool sel = (lane & 1) != 0;
    #pragma unroll
    for (int r = 0; r < 8; ++r) {
        float a = s[r], b = s[r + 8];
        s[r]     = sel ? b : a;
        s[r + 8] = sel ? a : b;
    }
}
template<int PC, int PT>
__device__ __forceinline__ void cnot_reg(float (&s)[NREG]) {
    #pragma unroll
    for (int r = 0; r < NREG; ++r) {
        if (((r >> PC) & 1) && !((r >> PT) & 1)) {
            float t = s[r];
            s[r] = s[r ^ (1 << PT)];
            s[r ^ (1 << PT)] = t;
        }
    }
}
__device__ __forceinline__ void perm_even(float (&s)[NREG], int lane) {
    int src = lane ^ (((((lane >> 5) & 1) << 4)) | ((((lane >> 3) & 1) << 2)) | (((lane >> 1) & 1)));
    #pragma unroll
    for (int r = 0; r < NREG; ++r) s[r] = __shfl(s[r], src);
}
__device__ __forceinline__ void perm_odd(float (&s)[NREG], int lane) {
    int src = lane ^ (((((lane >> 4) & 1) << 3)) | ((((lane >> 2) & 1) << 1)));
    #pragma unroll
    for (int r = 0; r < NREG; ++r) s[r] = __shfl(s[r], src);
}

#define APPLY_RY_ALL(CARR, SARR, BASE)                                        \
    { float c_, s_;                                                           \
      c_=__shfl(CARR,(BASE)+0); s_=__shfl(SARR,(BASE)+0); ry_lane<5>(s,lane,c_,s_); \
      c_=__shfl(CARR,(BASE)+1); s_=__shfl(SARR,(BASE)+1); ry_lane<4>(s,lane,c_,s_); \
      c_=__shfl(CARR,(BASE)+2); s_=__shfl(SARR,(BASE)+2); ry_lane<3>(s,lane,c_,s_); \
      c_=__shfl(CARR,(BASE)+3); s_=__shfl(SARR,(BASE)+3); ry_lane<2>(s,lane,c_,s_); \
      c_=__shfl(CARR,(BASE)+4); s_=__shfl(SARR,(BASE)+4); ry_lane<1>(s,lane,c_,s_); \
      c_=__shfl(CARR,(BASE)+5); s_=__shfl(SARR,(BASE)+5); ry_lane<0>(s,lane,c_,s_); \
      c_=__shfl(CARR,(BASE)+6); s_=__shfl(SARR,(BASE)+6); ry_reg<3>(s,c_,s_);       \
      c_=__shfl(CARR,(BASE)+7); s_=__shfl(SARR,(BASE)+7); ry_reg<2>(s,c_,s_);       \
      c_=__shfl(CARR,(BASE)+8); s_=__shfl(SARR,(BASE)+8); ry_reg<1>(s,c_,s_);       \
      c_=__shfl(CARR,(BASE)+9); s_=__shfl(SARR,(BASE)+9); ry_reg<0>(s,c_,s_); }

__device__ __forceinline__ void async16(const void* g, void* l) {
    __builtin_amdgcn_global_load_lds(
        (const __attribute__((address_space(1))) void*)g,
        (__attribute__((address_space(3))) void*)l, 16, 0, 0);
}

// ---------------------------------------------------------------- KA
__global__ __launch_bounds__(256) void ka_prepare(
    const float* __restrict__ X, const float* __restrict__ Wpre,
    const float* __restrict__ bpre, const float* __restrict__ qp,
    f16* __restrict__ psi0, f16* __restrict__ Arm, int B)
{
    const int tid = threadIdx.x, lane = tid & 63, wv = tid >> 6;

    // ---- psi0: 4 samples per wave (512 blocks x 16 = 8192)
    for (int it = 0; it < 4; ++it) {
        int sample = blockIdx.x * 16 + wv * 4 + it;
        if (sample >= B) break;
        const float* xrow = X + (size_t)sample * 512;
        float4 x0 = ((const float4*)xrow)[lane];
        float4 x1 = ((const float4*)xrow)[64 + lane];
        float acc[NQ];
        #pragma unroll
        for (int q = 0; q < NQ; ++q) {
            const float* wr = Wpre + q * 512;
            float4 w0 = ((const float4*)wr)[lane];
            float4 w1 = ((const float4*)wr)[64 + lane];
            float a = x0.x * w0.x;
            a = fmaf(x0.y, w0.y, a); a = fmaf(x0.z, w0.z, a); a = fmaf(x0.w, w0.w, a);
            a = fmaf(x1.x, w1.x, a); a = fmaf(x1.y, w1.y, a);
            a = fmaf(x1.z, w1.z, a); a = fmaf(x1.w, w1.w, a);
            acc[q] = a;
        }
        #pragma unroll
        for (int q = 0; q < NQ; ++q) {
            float v = acc[q];
            #pragma unroll
            for (int d = 32; d >= 1; d >>= 1) v += __shfl_xor(v, d);
            acc[q] = v;
        }
        float pre = acc[0];
        #pragma unroll
        for (int q = 1; q < NQ; ++q) pre = (lane == q) ? acc[q] : pre;
        float c45 = 0.0f, s45 = 0.0f;
        if (lane < NQ) {
            float th = tanhf(pre + bpre[lane]) * 1.5707963267948966f;
            sincosf(0.5f * th + 0.7853981633974483f, &s45, &c45);
        }
        float lv = 1.0f;
        #pragma unroll
        for (int w = 0; w < 6; ++w) {
            float f0 = __shfl(c45, w), f1 = __shfl(s45, w);
            lv *= ((lane >> (5 - w)) & 1) ? f1 : f0;
        }
        float c6 = __shfl(c45, 6), s6 = __shfl(s45, 6);
        float c7 = __shfl(c45, 7), s7 = __shfl(s45, 7);
        float c8 = __shfl(c45, 8), s8 = __shfl(s45, 8);
        float c9 = __shfl(c45, 9), s9 = __shfl(s45, 9);
        float g01[4] = {c6 * c7, c6 * s7, s6 * c7, s6 * s7};
        float g23[4] = {c8 * c9, c8 * s9, s8 * c9, s8 * s9};
        union { f16 h[16]; float4 v[2]; } u;
        #pragma unroll
        for (int r = 0; r < NREG; ++r)
            u.h[r] = (f16)(lv * g01[r >> 2] * g23[r & 3]);
        float4* dst = (float4*)((char*)psi0 + (size_t)sample * 2048 + lane * 32);
        dst[0] = u.v[0];
        dst[1] = u.v[1];
    }

    // ---- Arm rows: waves 0,1 build row (blockIdx*2 + wv)
    if (wv < 2) {
        int row = blockIdx.x * 2 + wv;
        if (row < DIM) {
            float cw = 1.0f, swn = 0.0f;
            if (lane < 60) {
                float s_, c_;
                sincosf(0.5f * qp[10 + lane], &s_, &c_);
                cw = c_; swn = -s_;
            }
            float s[NREG];
            int srcLane = row >> 4, srcReg = row & 15;
            #pragma unroll
            for (int r = 0; r < NREG; ++r)
                s[r] = (lane == srcLane && r == srcReg) ? 1.0f : 0.0f;
            for (int kk = 6; kk >= 1; --kk) {
                APPLY_RY_ALL(cw, swn, (kk - 1) * 10);
                perm_odd(s, lane);
                cnot_5_6(s, lane);
                cnot_reg<2, 1>(s);
                perm_even(s, lane);
                cnot_reg<3, 2>(s);
                cnot_reg<1, 0>(s);
            }
            union { f16 h[16]; float4 v[2]; } u;
            #pragma unroll
            for (int r = 0; r < NREG; ++r) u.h[r] = (f16)s[r];
            float4* dst = (float4*)((char*)Arm + (size_t)row * 2048 + lane * 32);
            dst[0] = u.v[0];
            dst[1] = u.v[1];
        }
    }
}

// ---------------------------------------------------------------- KB
__global__ __launch_bounds__(256, 2) void kb_gemm_measure(
    const f16* __restrict__ psi0, const f16* __restrict__ Arm,
    float* __restrict__ zpart)
{
    __shared__ __align__(16) char smem[32768];  // As 16K | Bs 16K ; reused as zbuf
    const int tid = threadIdx.x, lane = tid & 63, wv = tid >> 6;

    const int mB = blockIdx.x & 63, nB = blockIdx.x >> 6;
    const size_t tM = (size_t)mB * 128, tN = (size_t)nB * 128;
    f16* As = (f16*)smem;
    f16* Bs = (f16*)(smem + 16384);
    const int wm = (wv >> 1) * 64, wn = (wv & 1) * 64;

    f32x4 acc[4][4] = {};

    const f16* ga[4]; const f16* gb[4]; int ldso[4];
    #pragma unroll
    for (int p = 0; p < 4; ++p) {
        int slot = p * 256 + tid;
        int row = slot >> 3, gp = slot & 7, g = gp ^ (row & 7);
        ga[p] = psi0 + (tM + row) * 1024 + g * 8;
        gb[p] = Arm  + (tN + row) * 1024 + g * 8;
        ldso[p] = slot * 16;  // byte offset in LDS
    }

    for (int kt = 0; kt < 1024; kt += 64) {
        __syncthreads();
        #pragma unroll
        for (int p = 0; p < 4; ++p) async16(ga[p] + kt, (char*)As + ldso[p]);
        #pragma unroll
        for (int p = 0; p < 4; ++p) async16(gb[p] + kt, (char*)Bs + ldso[p]);
        __syncthreads();
        #pragma unroll
        for (int ks = 0; ks < 2; ++ks) {
            f16x8 af[4], bf[4];
            const int gpb = ks * 4 + (lane >> 4);
            const int gpx = gpb ^ (lane & 7);
            #pragma unroll
            for (int i = 0; i < 4; ++i) {
                int rowA = wm + i * 16 + (lane & 15);
                af[i] = *(const f16x8*)(As + rowA * 64 + gpx * 8);
            }
            #pragma unroll
            for (int j = 0; j < 4; ++j) {
                int rowB = wn + j * 16 + (lane & 15);
                bf[j] = *(const f16x8*)(Bs + rowB * 64 + gpx * 8);
            }
            #pragma unroll
            for (int i = 0; i < 4; ++i)
                #pragma unroll
                for (int j = 0; j < 4; ++j)
                    acc[i][j] = __builtin_amdgcn_mfma_f32_16x16x32_f16(af[i], bf[j], acc[i][j], 0, 0, 0);
        }
    }

    __syncthreads();  // done with As/Bs; reuse as zbuf[2][128][10] f32
    float* zb = (float*)smem + (wn ? 1280 : 0);
    const float sg0 = (nB & 4) ? -1.0f : 1.0f;  // wire0 <- n[9]
    const float sg1 = (nB & 2) ? -1.0f : 1.0f;  // wire1 <- n[8]
    const float sg2 = (nB & 1) ? -1.0f : 1.0f;  // wire2 <- n[7]
    const float sg3 = wn ? -1.0f : 1.0f;        // wire3 <- n[6]

    #pragma unroll
    for (int i = 0; i < 4; ++i) {
        #pragma unroll
        for (int t = 0; t < 4; ++t) {
            float p0 = acc[i][0][t] * acc[i][0][t];
            float p1 = acc[i][1][t] * acc[i][1][t];
            float p2 = acc[i][2][t] * acc[i][2][t];
            float p3 = acc[i][3][t] * acc[i][3][t];
            float t0  = (p0 + p1) + (p2 + p3);
            float tw5 = (p0 - p1) + (p2 - p3);  // wire5 <- n[4] = j&1
            float tw4 = (p0 + p1) - (p2 + p3);  // wire4 <- n[5] = j>>1
            // butterfly over lane bits 0..3 = n[0..3] -> wires 9,8,7,6
            float s1 = __shfl_xor(t0, 1);
            float Av = t0 + s1;
            float Bv = (lane & 1) ? s1 - t0 : t0 - s1;
            float sA = __shfl_xor(Av, 2), sB = __shfl_xor(Bv, 2);
            float AP = Av + sA;
            float AM = (lane & 2) ? sA - Av : Av - sA;
            float BP = Bv + sB;
            float sAP = __shfl_xor(AP, 4), sAM = __shfl_xor(AM, 4), sBP = __shfl_xor(BP, 4);
            float APP = AP + sAP;
            float APM = (lane & 4) ? sAP - AP : AP - sAP;
            float AMP = AM + sAM;
            float BPP = BP + sBP;
            float a1 = __shfl_xor(APP, 8), a2 = __shfl_xor(APM, 8);
            float a3 = __shfl_xor(AMP, 8), a4 = __shfl_xor(BPP, 8);
            float T0 = APP + a1;
            float S6 = (lane & 8) ? a1 - APP : APP - a1;
            float S7 = APM + a2;
            float S8 = AMP + a3;
            float S9 = BPP + a4;
            float T5 = tw5, T4 = tw4;
            T5 += __shfl_xor(T5, 1); T5 += __shfl_xor(T5, 2);
            T5 += __shfl_xor(T5, 4); T5 += __shfl_xor(T5, 8);
            T4 += __shfl_xor(T4, 1); T4 += __shfl_xor(T4, 2);
            T4 += __shfl_xor(T4, 4); T4 += __shfl_xor(T4, 8);
            if ((lane & 15) == 0) {
                int row = wm + i * 16 + (lane >> 4) * 4 + t;
                float* d = zb + row * 10;
                d[0] = sg0 * T0; d[1] = sg1 * T0; d[2] = sg2 * T0; d[3] = sg3 * T0;
                d[4] = T4; d[5] = T5;
                d[6] = S6; d[7] = S7; d[8] = S8; d[9] = S9;
            }
        }
    }
    __syncthreads();
    // combine col-halves, store zpart[nB][tM+row][10]
    float* zall = (float*)smem;
    for (int idx = tid; idx < 1280; idx += 256) {
        float v = zall[idx] + zall[1280 + idx];
        int row = idx / 10, w = idx - row * 10;
        zpart[((size_t)nB * 8192 + tM + row) * 10 + w] = v;
    }
}

// ---------------------------------------------------------------- KC
__global__ __launch_bounds__(256) void kc_post(
    const float* __restrict__ zpart, const float* __restrict__ Wpost,
    const float* __restrict__ bpost, float* __restrict__ out, int B)
{
    int gid = blockIdx.x * 256 + threadIdx.x;
    if (gid >= B) return;
    float z[NQ] = {};
    #pragma unroll
    for (int nb = 0; nb < 8; ++nb) {
        const float* zp = zpart + ((size_t)nb * 8192 + gid) * 10;
        #pragma unroll
        for (int w = 0; w < NQ; ++w) z[w] += zp[w];
    }
    float o0 = bpost[0], o1 = bpost[1];
    #pragma unroll
    for (int w = 0; w < NQ; ++w) {
        o0 = fmaf(z[w], Wpost[w], o0);
        o1 = fmaf(z[w], Wpost[NQ + w], o1);
    }
    out[(size_t)gid * 2 + 0] = o0;
    out[(size_t)gid * 2 + 1] = o1;
}

// ---------------------------------------------------------------- fallback (R1, verified)
template<int BC, int BT>
__device__ __forceinline__ void cnot_lane(float (&s)[NREG], int lane) {
    int src = ((lane >> BC) & 1) ? (lane ^ (1 << BT)) : lane;
    #pragma unroll
    for (int r = 0; r < NREG; ++r) s[r] = __shfl(s[r], src);
}

__global__ __launch_bounds__(256) void hybrid_head_fallback(
    const float* __restrict__ X, const float* __restrict__ Wpre,
    const float* __restrict__ bpre, const float* __restrict__ qp,
    const float* __restrict__ Wpost, const float* __restrict__ bpost,
    float* __restrict__ out, int B)
{
    const int lane = threadIdx.x & 63;
    const int wave = threadIdx.x >> 6;
    const int sample = blockIdx.x * 4 + wave;
    if (sample >= B) return;

    const float* xrow = X + (size_t)sample * 512;
    float4 x0 = ((const float4*)xrow)[lane];
    float4 x1 = ((const float4*)xrow)[64 + lane];
    float acc[NQ];
    #pragma unroll
    for (int q = 0; q < NQ; ++q) {
        const float* wr = Wpre + q * 512;
        float4 w0 = ((const float4*)wr)[lane];
        float4 w1 = ((const float4*)wr)[64 + lane];
        float a = x0.x * w0.x;
        a = fmaf(x0.y, w0.y, a); a = fmaf(x0.z, w0.z, a); a = fmaf(x0.w, w0.w, a);
        a = fmaf(x1.x, w1.x, a); a = fmaf(x1.y, w1.y, a);
        a = fmaf(x1.z, w1.z, a); a = fmaf(x1.w, w1.w, a);
        acc[q] = a;
    }
    #pragma unroll
    for (int q = 0; q < NQ; ++q) {
        float v = acc[q];
        #pragma unroll
        for (int d = 32; d >= 1; d >>= 1) v += __shfl_xor(v, d);
        acc[q] = v;
    }
    float pre = acc[0];
    #pragma unroll
    for (int q = 1; q < NQ; ++q) pre = (lane == q) ? acc[q] : pre;
    float cth = 1.0f, sth = 0.0f;
    if (lane < NQ) {
        float th = tanhf(pre + bpre[lane]) * 1.5707963267948966f;
        sincosf(0.5f * th, &sth, &cth);
    }
    float cw = 1.0f, sw = 0.0f;
    if (lane < 60) sincosf(0.5f * qp[10 + lane], &sw, &cw);

    float s[NREG];
    #pragma unroll
    for (int r = 0; r < NREG; ++r) s[r] = 0.03125f;
    APPLY_RY_ALL(cth, sth, 0);
    for (int k = 0; k < 6; ++k) {
        perm_even(s, lane);
        cnot_reg<3, 2>(s);
        cnot_reg<1, 0>(s);
        perm_odd(s, lane);
        cnot_5_6(s, lane);
        cnot_reg<2, 1>(s);
        APPLY_RY_ALL(cw, sw, k * 10);
    }
    float p[NREG], tot = 0.0f;
    #pragma unroll
    for (int r = 0; r < NREG; ++r) { p[r] = s[r] * s[r]; tot += p[r]; }
    float z[NQ];
    #pragma unroll
    for (int w = 0; w < 6; ++w) z[w] = ((lane >> (5 - w)) & 1) ? -tot : tot;
    z[6] = z[7] = z[8] = z[9] = 0.0f;
    #pragma unroll
    for (int r = 0; r < NREG; ++r) {
        z[6] += ((r >> 3) & 1) ? -p[r] : p[r];
        z[7] += ((r >> 2) & 1) ? -p[r] : p[r];
        z[8] += ((r >> 1) & 1) ? -p[r] : p[r];
        z[9] += ((r >> 0) & 1) ? -p[r] : p[r];
    }
    #pragma unroll
    for (int w = 0; w < NQ; ++w) {
        float v = z[w];
        #pragma unroll
        for (int d = 32; d >= 1; d >>= 1) v += __shfl_xor(v, d);
        z[w] = v;
    }
    if (lane < 2) {
        const float* wp = Wpost + lane * NQ;
        float o = bpost[lane];
        #pragma unroll
        for (int w = 0; w < NQ; ++w) o = fmaf(z[w], wp[w], o);
        out[(size_t)sample * 2 + lane] = o;
    }
}

// ---------------------------------------------------------------- launch
extern "C" void kernel_launch(void* const* d_in, const int* in_sizes, int n_in,
                              void* d_out, int out_size, void* d_ws, size_t ws_size,
                              hipStream_t stream) {
    const float* X     = (const float*)d_in[0];
    const float* Wpre  = (const float*)d_in[1];
    const float* bpre  = (const float*)d_in[2];
    const float* qp    = (const float*)d_in[3];
    const float* Wpost = (const float*)d_in[4];
    const float* bpost = (const float*)d_in[5];
    float* out = (float*)d_out;
    int B = in_sizes[0] / 512;  // 8192

    size_t psi0_b  = (size_t)B * DIM * sizeof(f16);          // 16 MB
    size_t arm_b   = (size_t)DIM * DIM * sizeof(f16);        // 2 MB
    size_t zpart_b = (size_t)8 * 8192 * 10 * sizeof(float);  // 2.6 MB
    size_t need = psi0_b + arm_b + zpart_b;

    if (B != 8192 || ws_size < need) {
        hipLaunchKernelGGL(hybrid_head_fallback, dim3((B + 3) / 4), dim3(256), 0, stream,
                           X, Wpre, bpre, qp, Wpost, bpost, out, B);
        return;
    }

    char* ws = (char*)d_ws;
    f16*   psi0  = (f16*)ws;
    f16*   Arm   = (f16*)(ws + psi0_b);
    float* zpart = (float*)(ws + psi0_b + arm_b);

    hipLaunchKernelGGL(ka_prepare, dim3(512), dim3(256), 0, stream,
                       X, Wpre, bpre, qp, psi0, Arm, B);
    hipLaunchKernelGGL(kb_gemm_measure, dim3(512), dim3(256), 0, stream,
                       psi0, Arm, zpart);
    hipLaunchKernelGGL(kc_post, dim3(32), dim3(256), 0, stream,
                       zpart, Wpost, bpost, out, B);
}

// Round 6
// 124.897 us; speedup vs baseline: 1.4540x; 1.0106x over previous
//
#include <hip/hip_runtime.h>
#include <math.h>

// BaseHybridHead, 3 stream-ordered kernels:
//  KA: pre-GEMM + rank-1 expand -> psi0 (8192x1024 f16); Arm rows (1024x1024 f16);
//      zero z[8192][10]
//  KB: MFMA GEMM psif = psi0 @ Arm^T (64x128 tiles, BK=64, XOR-swizzled LDS,
//      4 blocks/CU) with fused +-square measurement epilogue -> atomicAdd z
//  KC: out = z @ Wpost^T + bpost

#define NQ   10
#define NREG 16
#define DIM  1024

typedef _Float16 f16;
typedef _Float16 f16x8 __attribute__((ext_vector_type(8)));
typedef float    f32x4 __attribute__((ext_vector_type(4)));

// ---------------------------------------------------------------- gate ops
template<int BB>
__device__ __forceinline__ void ry_lane(float (&s)[NREG], int lane, float c, float si) {
    float sgn = ((lane >> BB) & 1) ? si : -si;
    #pragma unroll
    for (int r = 0; r < NREG; ++r) {
        float o = __shfl_xor(s[r], 1 << BB);
        s[r] = fmaf(sgn, o, c * s[r]);
    }
}
template<int P>
__device__ __forceinline__ void ry_reg(float (&s)[NREG], float c, float si) {
    const int m = 1 << P;
    #pragma unroll
    for (int r = 0; r < NREG; ++r) {
        if ((r & m) == 0) {
            float a = s[r], b = s[r + m];
            s[r]     = fmaf(c, a, -si * b);
            s[r + m] = fmaf(si, a,  c * b);
        }
    }
}
__device__ __forceinline__ void cnot_5_6(float (&s)[NREG], int lane) {
    bool sel = (lane & 1) != 0;
    #pragma unroll
    for (int r = 0; r < 8; ++r) {
        float a = s[r], b = s[r + 8];
        s[r]     = sel ? b : a;
        s[r + 8] = sel ? a : b;
    }
}
template<int PC, int PT>
__device__ __forceinline__ void cnot_reg(float (&s)[NREG]) {
    #pragma unroll
    for (int r = 0; r < NREG; ++r) {
        if (((r >> PC) & 1) && !((r >> PT) & 1)) {
            float t = s[r];
            s[r] = s[r ^ (1 << PT)];
            s[r ^ (1 << PT)] = t;
        }
    }
}
__device__ __forceinline__ void perm_even(float (&s)[NREG], int lane) {
    int src = lane ^ (((((lane >> 5) & 1) << 4)) | ((((lane >> 3) & 1) << 2)) | (((lane >> 1) & 1)));
    #pragma unroll
    for (int r = 0; r < NREG; ++r) s[r] = __shfl(s[r], src);
}
__device__ __forceinline__ void perm_odd(float (&s)[NREG], int lane) {
    int src = lane ^ (((((lane >> 4) & 1) << 3)) | ((((lane >> 2) & 1) << 1)));
    #pragma unroll
    for (int r = 0; r < NREG; ++r) s[r] = __shfl(s[r], src);
}

#define APPLY_RY_ALL(CARR, SARR, BASE)                                        \
    { float c_, s_;                                                           \
      c_=__shfl(CARR,(BASE)+0); s_=__shfl(SARR,(BASE)+0); ry_lane<5>(s,lane,c_,s_); \
      c_=__shfl(CARR,(BASE)+1); s_=__shfl(SARR,(BASE)+1); ry_lane<4>(s,lane,c_,s_); \
      c_=__shfl(CARR,(BASE)+2); s_=__shfl(SARR,(BASE)+2); ry_lane<3>(s,lane,c_,s_); \
      c_=__shfl(CARR,(BASE)+3); s_=__shfl(SARR,(BASE)+3); ry_lane<2>(s,lane,c_,s_); \
      c_=__shfl(CARR,(BASE)+4); s_=__shfl(SARR,(BASE)+4); ry_lane<1>(s,lane,c_,s_); \
      c_=__shfl(CARR,(BASE)+5); s_=__shfl(SARR,(BASE)+5); ry_lane<0>(s,lane,c_,s_); \
      c_=__shfl(CARR,(BASE)+6); s_=__shfl(SARR,(BASE)+6); ry_reg<3>(s,c_,s_);       \
      c_=__shfl(CARR,(BASE)+7); s_=__shfl(SARR,(BASE)+7); ry_reg<2>(s,c_,s_);       \
      c_=__shfl(CARR,(BASE)+8); s_=__shfl(SARR,(BASE)+8); ry_reg<1>(s,c_,s_);       \
      c_=__shfl(CARR,(BASE)+9); s_=__shfl(SARR,(BASE)+9); ry_reg<0>(s,c_,s_); }

__device__ __forceinline__ void async16(const void* g, void* l) {
    __builtin_amdgcn_global_load_lds(
        (const __attribute__((address_space(1))) void*)g,
        (__attribute__((address_space(3))) void*)l, 16, 0, 0);
}

// ---------------------------------------------------------------- KA
__global__ __launch_bounds__(256) void ka_prepare(
    const float* __restrict__ X, const float* __restrict__ Wpre,
    const float* __restrict__ bpre, const float* __restrict__ qp,
    f16* __restrict__ psi0, f16* __restrict__ Arm, float* __restrict__ z, int B)
{
    const int tid = threadIdx.x, lane = tid & 63, wv = tid >> 6;

    // ---- zero z accumulator (8192*10 floats; 512 blocks x 256 threads cover)
    {
        int idx = blockIdx.x * 256 + tid;
        if (idx < 8192 * NQ) z[idx] = 0.0f;
    }

    // ---- psi0: 4 samples per wave (512 blocks x 16 = 8192)
    for (int it = 0; it < 4; ++it) {
        int sample = blockIdx.x * 16 + wv * 4 + it;
        if (sample >= B) break;
        const float* xrow = X + (size_t)sample * 512;
        float4 x0 = ((const float4*)xrow)[lane];
        float4 x1 = ((const float4*)xrow)[64 + lane];
        float acc[NQ];
        #pragma unroll
        for (int q = 0; q < NQ; ++q) {
            const float* wr = Wpre + q * 512;
            float4 w0 = ((const float4*)wr)[lane];
            float4 w1 = ((const float4*)wr)[64 + lane];
            float a = x0.x * w0.x;
            a = fmaf(x0.y, w0.y, a); a = fmaf(x0.z, w0.z, a); a = fmaf(x0.w, w0.w, a);
            a = fmaf(x1.x, w1.x, a); a = fmaf(x1.y, w1.y, a);
            a = fmaf(x1.z, w1.z, a); a = fmaf(x1.w, w1.w, a);
            acc[q] = a;
        }
        #pragma unroll
        for (int q = 0; q < NQ; ++q) {
            float v = acc[q];
            #pragma unroll
            for (int d = 32; d >= 1; d >>= 1) v += __shfl_xor(v, d);
            acc[q] = v;
        }
        float pre = acc[0];
        #pragma unroll
        for (int q = 1; q < NQ; ++q) pre = (lane == q) ? acc[q] : pre;
        float c45 = 0.0f, s45 = 0.0f;
        if (lane < NQ) {
            float th = tanhf(pre + bpre[lane]) * 1.5707963267948966f;
            sincosf(0.5f * th + 0.7853981633974483f, &s45, &c45);
        }
        float lv = 1.0f;
        #pragma unroll
        for (int w = 0; w < 6; ++w) {
            float f0 = __shfl(c45, w), f1 = __shfl(s45, w);
            lv *= ((lane >> (5 - w)) & 1) ? f1 : f0;
        }
        float c6 = __shfl(c45, 6), s6 = __shfl(s45, 6);
        float c7 = __shfl(c45, 7), s7 = __shfl(s45, 7);
        float c8 = __shfl(c45, 8), s8 = __shfl(s45, 8);
        float c9 = __shfl(c45, 9), s9 = __shfl(s45, 9);
        float g01[4] = {c6 * c7, c6 * s7, s6 * c7, s6 * s7};
        float g23[4] = {c8 * c9, c8 * s9, s8 * c9, s8 * s9};
        union { f16 h[16]; float4 v[2]; } u;
        #pragma unroll
        for (int r = 0; r < NREG; ++r)
            u.h[r] = (f16)(lv * g01[r >> 2] * g23[r & 3]);
        float4* dst = (float4*)((char*)psi0 + (size_t)sample * 2048 + lane * 32);
        dst[0] = u.v[0];
        dst[1] = u.v[1];
    }

    // ---- Arm rows: waves 0,1 build row (blockIdx*2 + wv)
    if (wv < 2) {
        int row = blockIdx.x * 2 + wv;
        if (row < DIM) {
            float cw = 1.0f, swn = 0.0f;
            if (lane < 60) {
                float s_, c_;
                sincosf(0.5f * qp[10 + lane], &s_, &c_);
                cw = c_; swn = -s_;
            }
            float s[NREG];
            int srcLane = row >> 4, srcReg = row & 15;
            #pragma unroll
            for (int r = 0; r < NREG; ++r)
                s[r] = (lane == srcLane && r == srcReg) ? 1.0f : 0.0f;
            for (int kk = 6; kk >= 1; --kk) {
                APPLY_RY_ALL(cw, swn, (kk - 1) * 10);
                perm_odd(s, lane);
                cnot_5_6(s, lane);
                cnot_reg<2, 1>(s);
                perm_even(s, lane);
                cnot_reg<3, 2>(s);
                cnot_reg<1, 0>(s);
            }
            union { f16 h[16]; float4 v[2]; } u;
            #pragma unroll
            for (int r = 0; r < NREG; ++r) u.h[r] = (f16)s[r];
            float4* dst = (float4*)((char*)Arm + (size_t)row * 2048 + lane * 32);
            dst[0] = u.v[0];
            dst[1] = u.v[1];
        }
    }
}

// ---------------------------------------------------------------- KB
// 64x128 (MxN) tile, BK=64, grid 1024 = 4 blocks/CU.
__global__ __launch_bounds__(256, 4) void kb_gemm_measure(
    const f16* __restrict__ psi0, const f16* __restrict__ Arm,
    float* __restrict__ z)
{
    __shared__ __align__(16) char smem[24576];  // As 8K | Bs 16K ; reused as zbuf
    const int tid = threadIdx.x, lane = tid & 63, wv = tid >> 6;

    const int mB = blockIdx.x & 127, nB = blockIdx.x >> 7;  // 128 x 8
    const size_t tM = (size_t)mB * 64, tN = (size_t)nB * 128;
    f16* As = (f16*)smem;                 // 64 rows x 64 k
    f16* Bs = (f16*)(smem + 8192);        // 128 rows x 64 k
    const int wm = (wv >> 1) * 32, wn = (wv & 1) * 64;

    f32x4 acc[2][4] = {};

    // staging: A = 512 slots (2/thread), B = 1024 slots (4/thread)
    const f16* ga[2]; int ldsoA[2];
    #pragma unroll
    for (int p = 0; p < 2; ++p) {
        int slot = p * 256 + tid;
        int row = slot >> 3, gp = slot & 7, g = gp ^ (row & 7);
        ga[p] = psi0 + (tM + row) * 1024 + g * 8;
        ldsoA[p] = slot * 16;
    }
    const f16* gb[4]; int ldsoB[4];
    #pragma unroll
    for (int p = 0; p < 4; ++p) {
        int slot = p * 256 + tid;
        int row = slot >> 3, gp = slot & 7, g = gp ^ (row & 7);
        gb[p] = Arm + (tN + row) * 1024 + g * 8;
        ldsoB[p] = slot * 16;
    }

    for (int kt = 0; kt < 1024; kt += 64) {
        __syncthreads();
        #pragma unroll
        for (int p = 0; p < 2; ++p) async16(ga[p] + kt, (char*)As + ldsoA[p]);
        #pragma unroll
        for (int p = 0; p < 4; ++p) async16(gb[p] + kt, (char*)Bs + ldsoB[p]);
        __syncthreads();
        #pragma unroll
        for (int ks = 0; ks < 2; ++ks) {
            f16x8 af[2], bf[4];
            const int gpb = ks * 4 + (lane >> 4);
            const int gpx = gpb ^ (lane & 7);
            #pragma unroll
            for (int i = 0; i < 2; ++i) {
                int rowA = wm + i * 16 + (lane & 15);
                af[i] = *(const f16x8*)(As + rowA * 64 + gpx * 8);
            }
            #pragma unroll
            for (int j = 0; j < 4; ++j) {
                int rowB = wn + j * 16 + (lane & 15);
                bf[j] = *(const f16x8*)(Bs + rowB * 64 + gpx * 8);
            }
            #pragma unroll
            for (int i = 0; i < 2; ++i)
                #pragma unroll
                for (int j = 0; j < 4; ++j)
                    acc[i][j] = __builtin_amdgcn_mfma_f32_16x16x32_f16(af[i], bf[j], acc[i][j], 0, 0, 0);
        }
    }

    __syncthreads();  // done with As/Bs; reuse as zbuf[2][64][10] f32
    float* zb = (float*)smem + (wn ? 640 : 0);
    const float sg0 = (nB & 4) ? -1.0f : 1.0f;  // wire0 <- n[9]
    const float sg1 = (nB & 2) ? -1.0f : 1.0f;  // wire1 <- n[8]
    const float sg2 = (nB & 1) ? -1.0f : 1.0f;  // wire2 <- n[7]
    const float sg3 = wn ? -1.0f : 1.0f;        // wire3 <- n[6]

    #pragma unroll
    for (int i = 0; i < 2; ++i) {
        #pragma unroll
        for (int t = 0; t < 4; ++t) {
            float p0 = acc[i][0][t] * acc[i][0][t];
            float p1 = acc[i][1][t] * acc[i][1][t];
            float p2 = acc[i][2][t] * acc[i][2][t];
            float p3 = acc[i][3][t] * acc[i][3][t];
            float t0  = (p0 + p1) + (p2 + p3);
            float tw5 = (p0 - p1) + (p2 - p3);  // wire5 <- n[4] = j&1
            float tw4 = (p0 + p1) - (p2 + p3);  // wire4 <- n[5] = j>>1
            // butterfly over lane bits 0..3 = n[0..3] -> wires 9,8,7,6
            float s1 = __shfl_xor(t0, 1);
            float Av = t0 + s1;
            float Bv = (lane & 1) ? s1 - t0 : t0 - s1;
            float sA = __shfl_xor(Av, 2), sB = __shfl_xor(Bv, 2);
            float AP = Av + sA;
            float AM = (lane & 2) ? sA - Av : Av - sA;
            float BP = Bv + sB;
            float sAP = __shfl_xor(AP, 4), sAM = __shfl_xor(AM, 4), sBP = __shfl_xor(BP, 4);
            float APP = AP + sAP;
            float APM = (lane & 4) ? sAP - AP : AP - sAP;
            float AMP = AM + sAM;
            float BPP = BP + sBP;
            float a1 = __shfl_xor(APP, 8), a2 = __shfl_xor(APM, 8);
            float a3 = __shfl_xor(AMP, 8), a4 = __shfl_xor(BPP, 8);
            float T0 = APP + a1;
            float S6 = (lane & 8) ? a1 - APP : APP - a1;
            float S7 = APM + a2;
            float S8 = AMP + a3;
            float S9 = BPP + a4;
            float T5 = tw5, T4 = tw4;
            T5 += __shfl_xor(T5, 1); T5 += __shfl_xor(T5, 2);
            T5 += __shfl_xor(T5, 4); T5 += __shfl_xor(T5, 8);
            T4 += __shfl_xor(T4, 1); T4 += __shfl_xor(T4, 2);
            T4 += __shfl_xor(T4, 4); T4 += __shfl_xor(T4, 8);
            if ((lane & 15) == 0) {
                int row = wm + i * 16 + (lane >> 4) * 4 + t;
                float* d = zb + row * 10;
                d[0] = sg0 * T0; d[1] = sg1 * T0; d[2] = sg2 * T0; d[3] = sg3 * T0;
                d[4] = T4; d[5] = T5;
                d[6] = S6; d[7] = S7; d[8] = S8; d[9] = S9;
            }
        }
    }
    __syncthreads();
    // combine col-halves, atomic-accumulate into z[tM+row][10]
    // (R5 bug: `if (tid < 640)` covered only 256 of 640 entries -> strided loop)
    float* zall = (float*)smem;
    for (int idx = tid; idx < 640; idx += 256) {
        float v = zall[idx] + zall[640 + idx];
        int row = idx / 10, w = idx - row * 10;
        atomicAdd(&z[((size_t)tM + row) * 10 + w], v);
    }
}

// ---------------------------------------------------------------- KC
__global__ __launch_bounds__(256) void kc_post(
    const float* __restrict__ z, const float* __restrict__ Wpost,
    const float* __restrict__ bpost, float* __restrict__ out, int B)
{
    int gid = blockIdx.x * 256 + threadIdx.x;
    if (gid >= B) return;
    const float* zp = z + (size_t)gid * NQ;
    float o0 = bpost[0], o1 = bpost[1];
    #pragma unroll
    for (int w = 0; w < NQ; ++w) {
        float zw = zp[w];
        o0 = fmaf(zw, Wpost[w], o0);
        o1 = fmaf(zw, Wpost[NQ + w], o1);
    }
    out[(size_t)gid * 2 + 0] = o0;
    out[(size_t)gid * 2 + 1] = o1;
}

// ---------------------------------------------------------------- fallback (R1, verified)
template<int BC, int BT>
__device__ __forceinline__ void cnot_lane(float (&s)[NREG], int lane) {
    int src = ((lane >> BC) & 1) ? (lane ^ (1 << BT)) : lane;
    #pragma unroll
    for (int r = 0; r < NREG; ++r) s[r] = __shfl(s[r], src);
}

__global__ __launch_bounds__(256) void hybrid_head_fallback(
    const float* __restrict__ X, const float* __restrict__ Wpre,
    const float* __restrict__ bpre, const float* __restrict__ qp,
    const float* __restrict__ Wpost, const float* __restrict__ bpost,
    float* __restrict__ out, int B)
{
    const int lane = threadIdx.x & 63;
    const int wave = threadIdx.x >> 6;
    const int sample = blockIdx.x * 4 + wave;
    if (sample >= B) return;

    const float* xrow = X + (size_t)sample * 512;
    float4 x0 = ((const float4*)xrow)[lane];
    float4 x1 = ((const float4*)xrow)[64 + lane];
    float acc[NQ];
    #pragma unroll
    for (int q = 0; q < NQ; ++q) {
        const float* wr = Wpre + q * 512;
        float4 w0 = ((const float4*)wr)[lane];
        float4 w1 = ((const float4*)wr)[64 + lane];
        float a = x0.x * w0.x;
        a = fmaf(x0.y, w0.y, a); a = fmaf(x0.z, w0.z, a); a = fmaf(x0.w, w0.w, a);
        a = fmaf(x1.x, w1.x, a); a = fmaf(x1.y, w1.y, a);
        a = fmaf(x1.z, w1.z, a); a = fmaf(x1.w, w1.w, a);
        acc[q] = a;
    }
    #pragma unroll
    for (int q = 0; q < NQ; ++q) {
        float v = acc[q];
        #pragma unroll
        for (int d = 32; d >= 1; d >>= 1) v += __shfl_xor(v, d);
        acc[q] = v;
    }
    float pre = acc[0];
    #pragma unroll
    for (int q = 1; q < NQ; ++q) pre = (lane == q) ? acc[q] : pre;
    float cth = 1.0f, sth = 0.0f;
    if (lane < NQ) {
        float th = tanhf(pre + bpre[lane]) * 1.5707963267948966f;
        sincosf(0.5f * th, &sth, &cth);
    }
    float cw = 1.0f, sw = 0.0f;
    if (lane < 60) sincosf(0.5f * qp[10 + lane], &sw, &cw);

    float s[NREG];
    #pragma unroll
    for (int r = 0; r < NREG; ++r) s[r] = 0.03125f;
    APPLY_RY_ALL(cth, sth, 0);
    for (int k = 0; k < 6; ++k) {
        perm_even(s, lane);
        cnot_reg<3, 2>(s);
        cnot_reg<1, 0>(s);
        perm_odd(s, lane);
        cnot_5_6(s, lane);
        cnot_reg<2, 1>(s);
        APPLY_RY_ALL(cw, sw, k * 10);
    }
    float p[NREG], tot = 0.0f;
    #pragma unroll
    for (int r = 0; r < NREG; ++r) { p[r] = s[r] * s[r]; tot += p[r]; }
    float z[NQ];
    #pragma unroll
    for (int w = 0; w < 6; ++w) z[w] = ((lane >> (5 - w)) & 1) ? -tot : tot;
    z[6] = z[7] = z[8] = z[9] = 0.0f;
    #pragma unroll
    for (int r = 0; r < NREG; ++r) {
        z[6] += ((r >> 3) & 1) ? -p[r] : p[r];
        z[7] += ((r >> 2) & 1) ? -p[r] : p[r];
        z[8] += ((r >> 1) & 1) ? -p[r] : p[r];
        z[9] += ((r >> 0) & 1) ? -p[r] : p[r];
    }
    #pragma unroll
    for (int w = 0; w < NQ; ++w) {
        float v = z[w];
        #pragma unroll
        for (int d = 32; d >= 1; d >>= 1) v += __shfl_xor(v, d);
        z[w] = v;
    }
    if (lane < 2) {
        const float* wp = Wpost + lane * NQ;
        float o = bpost[lane];
        #pragma unroll
        for (int w = 0; w < NQ; ++w) o = fmaf(z[w], wp[w], o);
        out[(size_t)sample * 2 + lane] = o;
    }
}

// ---------------------------------------------------------------- launch
extern "C" void kernel_launch(void* const* d_in, const int* in_sizes, int n_in,
                              void* d_out, int out_size, void* d_ws, size_t ws_size,
                              hipStream_t stream) {
    const float* X     = (const float*)d_in[0];
    const float* Wpre  = (const float*)d_in[1];
    const float* bpre  = (const float*)d_in[2];
    const float* qp    = (const float*)d_in[3];
    const float* Wpost = (const float*)d_in[4];
    const float* bpost = (const float*)d_in[5];
    float* out = (float*)d_out;
    int B = in_sizes[0] / 512;  // 8192

    size_t psi0_b = (size_t)B * DIM * sizeof(f16);      // 16 MB
    size_t arm_b  = (size_t)DIM * DIM * sizeof(f16);    // 2 MB
    size_t z_b    = (size_t)B * NQ * sizeof(float);     // 327 KB
    size_t need = psi0_b + arm_b + z_b;

    if (B != 8192 || ws_size < need) {
        hipLaunchKernelGGL(hybrid_head_fallback, dim3((B + 3) / 4), dim3(256), 0, stream,
                           X, Wpre, bpre, qp, Wpost, bpost, out, B);
        return;
    }

    char* ws = (char*)d_ws;
    f16*   psi0 = (f16*)ws;
    f16*   Arm  = (f16*)(ws + psi0_b);
    float* z    = (float*)(ws + psi0_b + arm_b);

    hipLaunchKernelGGL(ka_prepare, dim3(512), dim3(256), 0, stream,
                       X, Wpre, bpre, qp, psi0, Arm, z, B);
    hipLaunchKernelGGL(kb_gemm_measure, dim3(1024), dim3(256), 0, stream,
                       psi0, Arm, z);
    hipLaunchKernelGGL(kc_post, dim3(32), dim3(256), 0, stream,
                       z, Wpost, bpost, out, B);
}